// Round 15
// baseline (345.836 us; speedup 1.0000x reference)
//
#include <hip/hip_runtime.h>
#include <stdint.h>

typedef unsigned short u16;
typedef __attribute__((ext_vector_type(8))) __bf16 bf16x8;
typedef __attribute__((ext_vector_type(4))) float f32x4;
typedef __attribute__((ext_vector_type(2))) float f32x2;
typedef __attribute__((ext_vector_type(8))) u16 u16x8;
typedef __attribute__((ext_vector_type(4))) u16 u16x4;

#define DEV __device__ __forceinline__

DEV u16 f2b(float f) {
  union { float f; uint32_t u; } v; v.f = f;
  uint32_t u = v.u;
  return (u16)((u + 0x7fffu + ((u >> 16) & 1u)) >> 16);
}
DEV float b2f(u16 h) {
  union { uint32_t u; float f; } v; v.u = ((uint32_t)h) << 16;
  return v.f;
}
DEV float u2f(uint32_t u) {
  union { uint32_t u; float f; } v; v.u = u;
  return v.f;
}
// f32 -> fp8 e4m3 (OCP)
DEV uint8_t f2fp8(float f) {
  return (uint8_t)(__builtin_amdgcn_cvt_pk_fp8_f32(f, f, 0, false) & 0xff);
}
// fused fp8x16 gather-convert-FMA (8 cvt + 8 packed fma)
DEV void fma16f8(f32x2* acc, uint4 v, float w) {
  f32x2 wv = {w, w};
  const uint32_t* pv = (const uint32_t*)&v;
  #pragma unroll
  for (int j = 0; j < 4; ++j) {
    f32x2 lo = __builtin_amdgcn_cvt_pk_f32_fp8(pv[j], false);
    f32x2 hi = __builtin_amdgcn_cvt_pk_f32_fp8(pv[j], true);
    acc[2 * j]     += wv * lo;
    acc[2 * j + 1] += wv * hi;
  }
}

// ---------------- fused weight transpose: 8 regions, tiled 32x32 via LDS ----
__global__ __launch_bounds__(256) void wconv_kernel(
    const float* __restrict__ W0, const float* __restrict__ W1,
    const float* __restrict__ W2, const float* __restrict__ W3,
    const float* __restrict__ W4, const float* __restrict__ W5,
    const float* __restrict__ W6, const float* __restrict__ W7,
    u16* __restrict__ dst) {
  __shared__ float s[32][33];
  int bx = blockIdx.x;            // 0..3071
  int ct = bx / 24;               // column-tile 0..127
  int kt = bx - ct * 24;          // k-tile 0..23
  const float* Wsrc; int N; int rowbase; int c0;
  if (ct < 24)       { Wsrc = W0; N = 768; rowbase = 0;    c0 = ct; }
  else if (ct < 40)  { Wsrc = W1; N = 512; rowbase = 768;  c0 = ct - 24; }
  else if (ct < 48)  { Wsrc = W2; N = 256; rowbase = 1280; c0 = ct - 40; }
  else if (ct < 72)  { Wsrc = W3; N = 768; rowbase = 1536; c0 = ct - 48; }
  else if (ct < 96)  { Wsrc = W4; N = 768; rowbase = 2304; c0 = ct - 72; }
  else if (ct < 100) { Wsrc = W5; N = 128; rowbase = 3072; c0 = ct - 96; }
  else if (ct < 104) { Wsrc = W6; N = 64;  rowbase = 3200; c0 = ct - 100; }
  else               { Wsrc = W7; N = 768; rowbase = 3328; c0 = ct - 104; }
  const int tx = threadIdx.x & 31, ty = threadIdx.x >> 5;
  const int n = c0 * 32 + tx;
  const int k0 = kt * 32;
  #pragma unroll
  for (int j = 0; j < 4; ++j) {
    int k = k0 + ty + j * 8;
    s[ty + j * 8][tx] = (n < N) ? Wsrc[(size_t)k * N + n] : 0.0f;
  }
  __syncthreads();
  #pragma unroll
  for (int j = 0; j < 4; ++j) {
    int nr = c0 * 32 + ty + j * 8;
    dst[(size_t)(rowbase + nr) * 768 + k0 + tx] = f2b(s[tx][ty + j * 8]);
  }
}

// ---------------- layernorm (row of 768), 192 threads, float4 ----------------
DEV void ln_stats(float4 v, int t, float* red, float& mean, float& rstd) {
  float s = v.x + v.y + v.z + v.w;
  float s2 = v.x * v.x + v.y * v.y + v.z * v.z + v.w * v.w;
  #pragma unroll
  for (int m = 1; m < 64; m <<= 1) { s += __shfl_xor(s, m); s2 += __shfl_xor(s2, m); }
  if ((t & 63) == 0) { red[t >> 6] = s; red[3 + (t >> 6)] = s2; }
  __syncthreads();
  float S = red[0] + red[1] + red[2];
  float S2 = red[3] + red[4] + red[5];
  mean = S * (1.0f / 768.0f);
  float var = S2 * (1.0f / 768.0f) - mean * mean;
  rstd = rsqrtf(var + 1e-6f);
}
DEV void ln_emit(float4 v, float mean, float rstd, const float* __restrict__ g,
                 const float* __restrict__ b, u16* __restrict__ o, int t) {
  float4 gv = ((const float4*)g)[t], bv = ((const float4*)b)[t];
  u16x4 ov;
  ov[0] = f2b((v.x - mean) * rstd * gv.x + bv.x);
  ov[1] = f2b((v.y - mean) * rstd * gv.y + bv.y);
  ov[2] = f2b((v.z - mean) * rstd * gv.z + bv.z);
  ov[3] = f2b((v.w - mean) * rstd * gv.w + bv.w);
  *(u16x4*)(o + t * 4) = ov;
}

// fused: src3 rows -> qln (qn gains) AND fln tail (fn gains); stats computed once
__global__ __launch_bounds__(192) void ln_src3_kernel(const float* __restrict__ src3,
    const float* __restrict__ qg, const float* __restrict__ qb,
    const float* __restrict__ fg, const float* __restrict__ fb,
    u16* __restrict__ qln, u16* __restrict__ fln) {
  __shared__ float red[6];
  int row = blockIdx.x;                      // 0..Mq-1
  int bb = row / 9216, pos = row - bb * 9216;
  int t = threadIdx.x;
  float4 v = ((const float4*)(src3 + (size_t)row * 768))[t];
  float mean, rstd;
  ln_stats(v, t, red, mean, rstd);
  ln_emit(v, mean, rstd, qg, qb, qln + (size_t)row * 768, t);
  ln_emit(v, mean, rstd, fg, fb, fln + ((size_t)bb * 14592 + 5376 + pos) * 768, t);
}

// feat LN for src0/1/2 rows only (src3 tail handled by ln_src3_kernel)
__global__ __launch_bounds__(192) void ln_feat012_kernel(const float* __restrict__ s0,
    const float* __restrict__ s1, const float* __restrict__ s2,
    const float* __restrict__ g, const float* __restrict__ b, u16* __restrict__ out) {
  __shared__ float red[6];
  int row = blockIdx.x;                      // 0..2*5376-1
  int bb = row / 5376, pos = row - bb * 5376;
  const float* x;
  if (pos < 256)       x = s0 + ((size_t)bb * 256  + pos) * 768;
  else if (pos < 1280) x = s1 + ((size_t)bb * 1024 + (pos - 256)) * 768;
  else                 x = s2 + ((size_t)bb * 4096 + (pos - 1280)) * 768;
  int t = threadIdx.x;
  float4 v = ((const float4*)x)[t];
  float mean, rstd;
  ln_stats(v, t, red, mean, rstd);
  ln_emit(v, mean, rstd, g, b, out + ((size_t)bb * 14592 + pos) * 768, t);
}

__global__ __launch_bounds__(192) void ln_rows_b16_kernel(const u16* __restrict__ in,
    const float* __restrict__ g, const float* __restrict__ b, u16* __restrict__ out) {
  __shared__ float red[6];
  size_t row = blockIdx.x;
  int t = threadIdx.x;
  u16x4 r = *(const u16x4*)(in + row * 768 + t * 4);
  float4 v = {b2f(r[0]), b2f(r[1]), b2f(r[2]), b2f(r[3])};
  float mean, rstd;
  ln_stats(v, t, red, mean, rstd);
  ln_emit(v, mean, rstd, g, b, out + row * 768, t);
}

// ---------------- bf16 MFMA GEMM, 2-phase double-buffered prefetch ----------
enum { MODE_F32 = 0, MODE_BF16 = 1, MODE_FINAL = 2, MODE_FP8T = 3 };

template <int MODE, int NT, int LROW = 1>
__global__ __launch_bounds__(256) void gemm_kernel(
    const u16* __restrict__ A, const u16* __restrict__ Wt,
    const float* __restrict__ bias1, const float* __restrict__ bias2,
    int split, int nb, void* __restrict__ Cout, int N,
    const u16* __restrict__ attnb, const float* __restrict__ resid,
    const float* __restrict__ g1, const float* __restrict__ g2) {
  constexpr int K = 768;
  __shared__ u16 smem[4 * 128 * 64];
  const int t = threadIdx.x;
  const int lane = t & 63;
  const int w = t >> 6;
  const int wr = w >> 1, wc = w & 1;
  const int chunk = gridDim.x >> 3;
  const int tile = (blockIdx.x & 7) * chunk + (blockIdx.x >> 3);
  const int tm = tile / NT, tn = tile - tm * NT;
  const size_t m0 = (size_t)tm * 128;
  const int n0 = tn * 128;

  f32x4 acc[4][4] = {};

  auto STAGE = [&](int buf, int kt) {
    u16* sA = smem + buf * 16384;
    u16* sB = sA + 8192;
    #pragma unroll
    for (int i = 0; i < 4; ++i) {
      int ci = i * 256 + t;
      int row = ci >> 3, c8 = ci & 7;
      int kc = c8 ^ (row & 7);
      const u16* ga = A + (m0 + row) * K + kt + kc * 8;
      const u16* gb = Wt + ((size_t)n0 + row) * K + kt + kc * 8;
      __builtin_amdgcn_global_load_lds((const __attribute__((address_space(1))) void*)ga,
          (__attribute__((address_space(3))) void*)(sA + ci * 8), 16, 0, 0);
      __builtin_amdgcn_global_load_lds((const __attribute__((address_space(1))) void*)gb,
          (__attribute__((address_space(3))) void*)(sB + ci * 8), 16, 0, 0);
    }
  };

  STAGE(0, 0);
  __syncthreads();
  int cur = 0;
  for (int kt = 0; kt < K; kt += 64) {
    if (kt + 64 < K) STAGE(cur ^ 1, kt + 64);
    const u16* sA = smem + cur * 16384;
    const u16* sB = sA + 8192;
    #pragma unroll
    for (int ks = 0; ks < 2; ++ks) {
      bf16x8 af[4], bfr[4];
      #pragma unroll
      for (int m = 0; m < 4; ++m) {
        int row = wr * 64 + m * 16 + (lane & 15);
        int pc = (ks * 4 + (lane >> 4)) ^ (row & 7);
        af[m] = *(const bf16x8*)(sA + row * 64 + pc * 8);
      }
      #pragma unroll
      for (int n = 0; n < 4; ++n) {
        int row = wc * 64 + n * 16 + (lane & 15);
        int pc = (ks * 4 + (lane >> 4)) ^ (row & 7);
        bfr[n] = *(const bf16x8*)(sB + row * 64 + pc * 8);
      }
      #pragma unroll
      for (int m = 0; m < 4; ++m)
        #pragma unroll
        for (int n = 0; n < 4; ++n)
          acc[m][n] = __builtin_amdgcn_mfma_f32_16x16x32_bf16(af[m], bfr[n], acc[m][n], 0, 0, 0);
    }
    __syncthreads();
    cur ^= 1;
  }

  if constexpr (MODE == MODE_BF16) {
    #pragma unroll
    for (int m = 0; m < 4; ++m) {
      #pragma unroll
      for (int n = 0; n < 4; ++n) {
        int lcol = wc * 64 + n * 16 + (lane & 15);
        int gcol = n0 + lcol;
        float bv = (gcol < split) ? bias1[gcol] : ((gcol < nb) ? bias2[gcol - split] : 0.0f);
        #pragma unroll
        for (int r = 0; r < 4; ++r) {
          int lrow = wr * 64 + m * 16 + (lane >> 4) * 4 + r;
          smem[lrow * 136 + lcol] = f2b(acc[m][n][r] + bv);
        }
      }
    }
    __syncthreads();
    #pragma unroll
    for (int i = 0; i < 8; ++i) {
      int c = t + 256 * i;                 // 0..2047
      int lrow = c >> 4, col8 = (c & 15) * 8;
      u16x8 vv = *(const u16x8*)(smem + lrow * 136 + col8);
      int gcol = n0 + col8;
      size_t grow = m0 + (size_t)lrow;
      *(u16x8*)((u16*)Cout + grow * (size_t)N + gcol) = vv;
    }
  } else if constexpr (MODE == MODE_FP8T) {
    uint8_t* s8 = (uint8_t*)smem;          // 128 rows x 144B stride
    #pragma unroll
    for (int m = 0; m < 4; ++m) {
      #pragma unroll
      for (int n = 0; n < 4; ++n) {
        int lcol = wc * 64 + n * 16 + (lane & 15);
        int gcol = n0 + lcol;
        float bv = (gcol < split) ? bias1[gcol] : ((gcol < nb) ? bias2[gcol - split] : 0.0f);
        #pragma unroll
        for (int r = 0; r < 4; ++r) {
          int lrow = wr * 64 + m * 16 + (lane >> 4) * 4 + r;
          s8[lrow * 144 + lcol] = f2fp8(acc[m][n][r] + bv);
        }
      }
    }
    __syncthreads();
    #pragma unroll
    for (int i = 0; i < 4; ++i) {
      int c = t + 256 * i;                 // 0..1023
      int lrow = c >> 3, col16 = (c & 7) * 16;
      uint4 vv = *(const uint4*)(s8 + lrow * 144 + col16);
      int gcol = n0 + col16;
      size_t grow = m0 + (size_t)lrow;
      int gi = (int)grow;
      int bb = gi / LROW, pos = gi - bb * LROW;
      int hh = gcol / 48, dd = gcol - hh * 48;   // 16 | 48: never crosses a head
      *(uint4*)((uint8_t*)Cout + (((size_t)bb * 16 + hh) * LROW + pos) * 48 + dd) = vv;
    }
  } else {
    #pragma unroll
    for (int m = 0; m < 4; ++m) {
      #pragma unroll
      for (int n = 0; n < 4; ++n) {
        int col = n0 + wc * 64 + n * 16 + (lane & 15);
        float bv = (col < split) ? bias1[col] : ((col < nb) ? bias2[col - split] : 0.0f);
        #pragma unroll
        for (int r = 0; r < 4; ++r) {
          size_t grow = m0 + (size_t)(wr * 64 + m * 16 + (lane >> 4) * 4 + r);
          float v = acc[m][n][r] + bv;
          size_t idx = grow * (size_t)N + col;
          if constexpr (MODE == MODE_F32) {
            ((float*)Cout)[idx] = v;
          } else {
            ((float*)Cout)[idx] = resid[idx] + g1[col] * (b2f(attnb[idx]) + g2[col] * v);
          }
        }
      }
    }
  }
}

// ---------------- deformable sampling: fp8, d16 + point-split lanes ---------
// value: [b][16 heads][LROW][48] fp8 e4m3 head-major; offa bf16.
// 4 queries/block, 384 threads. Phase 1 (t<256, (q,h,l)): descriptors.
// Phase 2 (all 384, (q,h,d16,ph)): ph in {0,1} on ADJACENT lanes; each walks 8
// points; 16-wide __shfl_xor(.,1) merges partners (pairs never cross wave64).
// ph0 stores channels [0..7], ph1 stores [8..15].
__global__ __launch_bounds__(384, 4) void samp_c_kernel(const uint8_t* __restrict__ value,
    const u16* __restrict__ offa, u16* __restrict__ out) {
  __shared__ uint8_t sdesc[4 * 16 * 528];   // 33792 B
  const int orig = blockIdx.x;
  const int cpx = gridDim.x >> 3;
  const int bq0 = ((orig & 7) * cpx + (orig >> 3)) * 4;
  const int t = threadIdx.x;

  if (t < 256) {
    const int qi = t >> 6, h = (t >> 2) & 15, l = t & 3;
    const int bq = bq0 + qi;
    const int b = bq / 9216, q = bq - b * 9216;
    const u16* rw = offa + (size_t)bq * 768;
    u16x8 A0 = *(const u16x8*)(rw + 512 + h * 16);
    u16x8 A1 = *(const u16x8*)(rw + 512 + h * 16 + 8);
    float lg[16];
    #pragma unroll
    for (int i = 0; i < 8; ++i) { lg[i] = b2f(A0[i]); lg[8 + i] = b2f(A1[i]); }
    float mx = lg[0];
    #pragma unroll
    for (int i = 1; i < 16; ++i) mx = fmaxf(mx, lg[i]);
    float sum = 0.0f;
    #pragma unroll
    for (int i = 0; i < 16; ++i) sum += __expf(lg[i] - mx);
    const float rs = 1.0f / sum;
    float w0 = (l == 0) ? lg[0] : ((l == 1) ? lg[4] : ((l == 2) ? lg[8]  : lg[12]));
    float w1 = (l == 0) ? lg[1] : ((l == 1) ? lg[5] : ((l == 2) ? lg[9]  : lg[13]));
    float w2 = (l == 0) ? lg[2] : ((l == 1) ? lg[6] : ((l == 2) ? lg[10] : lg[14]));
    float w3 = (l == 0) ? lg[3] : ((l == 1) ? lg[7] : ((l == 2) ? lg[11] : lg[15]));

    const int Wd = (l == 3) ? 96 : (16 << l);
    const int STl = (l == 0) ? 0 : ((l == 1) ? 256 : ((l == 2) ? 1280 : 5376));
    const float fW = (float)Wd;
    const float rx = ((q % 96) + 0.5f) * (1.0f / 96.0f);
    const float ry = ((q / 96) + 0.5f) * (1.0f / 96.0f);
    const int headbase = (b * 16 + h) * 14592 + STl;

    u16x8 O = *(const u16x8*)(rw + h * 32 + l * 8);
    float oxs[4] = {b2f(O[0]), b2f(O[2]), b2f(O[4]), b2f(O[6])};
    float oys[4] = {b2f(O[1]), b2f(O[3]), b2f(O[5]), b2f(O[7])};
    float wgs[4] = {w0, w1, w2, w3};
    uint8_t* dpb = sdesc + (qi * 16 + h) * 528 + l * 32;   // slot = pt*4 + l
    #pragma unroll
    for (int pt = 0; pt < 4; ++pt) {
      float px = rx * fW + oxs[pt] - 0.5f;
      float py = ry * fW + oys[pt] - 0.5f;
      float wgt = __expf(wgs[pt] - mx) * rs;
      float x0f = floorf(px), y0f = floorf(py);
      float lx = px - x0f, ly = py - y0f;
      int x0 = (int)x0f, y0 = (int)y0f;
      int xc0 = min(max(x0, 0), Wd - 1), xc1 = min(max(x0 + 1, 0), Wd - 1);
      int yc0 = min(max(y0, 0), Wd - 1), yc1 = min(max(y0 + 1, 0), Wd - 1);
      float wx0 = ((unsigned)x0       < (unsigned)Wd) ? (1.0f - lx) : 0.0f;
      float wx1 = ((unsigned)(x0 + 1) < (unsigned)Wd) ? lx          : 0.0f;
      float wy0 = (((unsigned)y0       < (unsigned)Wd) ? (1.0f - ly) : 0.0f) * wgt;
      float wy1 = (((unsigned)(y0 + 1) < (unsigned)Wd) ? ly          : 0.0f) * wgt;
      int4 ii;
      ii.x = (headbase + yc0 * Wd + xc0) * 48;
      ii.y = (headbase + yc0 * Wd + xc1) * 48;
      ii.z = (headbase + yc1 * Wd + xc0) * 48;
      ii.w = (headbase + yc1 * Wd + xc1) * 48;
      float4 ww = {wx0 * wy0, wx1 * wy0, wx0 * wy1, wx1 * wy1};
      *(int4*)(dpb + pt * 128) = ii;
      *(float4*)(dpb + pt * 128 + 16) = ww;
    }
  }
  __syncthreads();

  const int qi = t / 96, r = t - qi * 96;
  const int h = r / 6, sub = r - h * 6;
  const int d16 = sub >> 1, ph = sub & 1;
  const int bq = bq0 + qi;
  const int hd = d16 * 16;
  const uint8_t* vB = value;
  const uint8_t* dp = sdesc + (qi * 16 + h) * 528 + ph * 256;   // points ph*8..+7

  f32x2 acc0[8] = {}, acc1[8] = {};
  #pragma unroll
  for (int p = 0; p < 8; ++p) {
    const uint8_t* dpp = dp + p * 32;
    int4   ii = *(const int4*)(dpp);
    float4 ww = *(const float4*)(dpp + 16);
    uint4 g0 = *(const uint4*)(vB + (ii.x + hd));
    uint4 g1 = *(const uint4*)(vB + (ii.y + hd));
    uint4 g2 = *(const uint4*)(vB + (ii.z + hd));
    uint4 g3 = *(const uint4*)(vB + (ii.w + hd));
    fma16f8(acc0, g0, ww.x);
    fma16f8(acc1, g1, ww.y);
    fma16f8(acc0, g2, ww.z);
    fma16f8(acc1, g3, ww.w);
  }
  // merge partner lanes (ph0 <-> ph1, adjacent lanes, same wave)
  float ch[16];
  #pragma unroll
  for (int j = 0; j < 8; ++j) {
    ch[2 * j]     = acc0[j][0] + acc1[j][0];
    ch[2 * j + 1] = acc0[j][1] + acc1[j][1];
  }
  #pragma unroll
  for (int j = 0; j < 16; ++j) ch[j] += __shfl_xor(ch[j], 1);
  u16x8 o;
  #pragma unroll
  for (int j = 0; j < 8; ++j) o[j] = f2b(ch[ph * 8 + j]);
  *(u16x8*)(out + (size_t)bq * 768 + h * 48 + d16 * 16 + ph * 8) = o;
}

// self-attn sampling: offa (bf16) row = [128 off | 64 logits | 64 pad], stride 256.
// value: [b][16][9216][48] fp8. 4 queries/block, 256 threads, d16 phase 2.
__global__ __launch_bounds__(256, 4) void samp_s_kernel(const uint8_t* __restrict__ value,
    const u16* __restrict__ offa, u16* __restrict__ out) {
  __shared__ uint8_t sdesc[4 * 16 * 144];   // 9216 B
  const int orig = blockIdx.x;
  const int cpx = gridDim.x >> 3;
  const int bq0 = ((orig & 7) * cpx + (orig >> 3)) * 4;
  const int t = threadIdx.x;

  if (t < 64) {
    const int qi = t >> 4, h = t & 15;
    const int bq = bq0 + qi;
    const int b = bq / 9216, q = bq - b * 9216;
    const u16* rw = offa + (size_t)bq * 256;
    u16x4 Lv = *(const u16x4*)(rw + 128 + h * 4);
    float lg[4] = {b2f(Lv[0]), b2f(Lv[1]), b2f(Lv[2]), b2f(Lv[3])};
    float mx = fmaxf(fmaxf(lg[0], lg[1]), fmaxf(lg[2], lg[3]));
    float sum = __expf(lg[0] - mx) + __expf(lg[1] - mx) + __expf(lg[2] - mx) + __expf(lg[3] - mx);
    const float rs = 1.0f / sum;
    const float rx = ((q % 96) + 0.5f) * (1.0f / 96.0f);
    const float ry = ((q / 96) + 0.5f) * (1.0f / 96.0f);
    const int headbase = (b * 16 + h) * 9216;
    u16x8 O = *(const u16x8*)(rw + h * 8);
    float oxs[4] = {b2f(O[0]), b2f(O[2]), b2f(O[4]), b2f(O[6])};
    float oys[4] = {b2f(O[1]), b2f(O[3]), b2f(O[5]), b2f(O[7])};
    uint8_t* dpb = sdesc + (qi * 16 + h) * 144;
    #pragma unroll
    for (int pt = 0; pt < 4; ++pt) {
      float px = rx * 96.0f + oxs[pt] - 0.5f;
      float py = ry * 96.0f + oys[pt] - 0.5f;
      float wgt = __expf(lg[pt] - mx) * rs;
      float x0f = floorf(px), y0f = floorf(py);
      float lx = px - x0f, ly = py - y0f;
      int x0 = (int)x0f, y0 = (int)y0f;
      int xc0 = min(max(x0, 0), 95), xc1 = min(max(x0 + 1, 0), 95);
      int yc0 = min(max(y0, 0), 95), yc1 = min(max(y0 + 1, 0), 95);
      float wx0 = ((unsigned)x0       < 96u) ? (1.0f - lx) : 0.0f;
      float wx1 = ((unsigned)(x0 + 1) < 96u) ? lx          : 0.0f;
      float wy0 = (((unsigned)y0       < 96u) ? (1.0f - ly) : 0.0f) * wgt;
      float wy1 = (((unsigned)(y0 + 1) < 96u) ? ly          : 0.0f) * wgt;
      int4 ii;
      ii.x = (headbase + yc0 * 96 + xc0) * 48;
      ii.y = (headbase + yc0 * 96 + xc1) * 48;
      ii.z = (headbase + yc1 * 96 + xc0) * 48;
      ii.w = (headbase + yc1 * 96 + xc1) * 48;
      float4 ww = {wx0 * wy0, wx1 * wy0, wx0 * wy1, wx1 * wy1};
      *(int4*)(dpb + pt * 32) = ii;
      *(float4*)(dpb + pt * 32 + 16) = ww;
    }
  }
  __syncthreads();
  if (t >= 192) return;

  const int qi = t / 48, r = t - qi * 48;
  const int h = r / 3, d16 = r - h * 3;
  const int bq = bq0 + qi;
  const int hd = d16 * 16;
  const uint8_t* vB = value;
  const uint8_t* dp = sdesc + (qi * 16 + h) * 144;

  f32x2 acc0[8] = {}, acc1[8] = {};
  #pragma unroll
  for (int p = 0; p < 4; ++p) {
    const uint8_t* dpp = dp + p * 32;
    int4   ii = *(const int4*)(dpp);
    float4 ww = *(const float4*)(dpp + 16);
    uint4 g0 = *(const uint4*)(vB + (ii.x + hd));
    uint4 g1 = *(const uint4*)(vB + (ii.y + hd));
    uint4 g2 = *(const uint4*)(vB + (ii.z + hd));
    uint4 g3 = *(const uint4*)(vB + (ii.w + hd));
    fma16f8(acc0, g0, ww.x);
    fma16f8(acc1, g1, ww.y);
    fma16f8(acc0, g2, ww.z);
    fma16f8(acc1, g3, ww.w);
  }
  u16x8 o0, o1;
  #pragma unroll
  for (int j = 0; j < 4; ++j) {
    o0[2*j]   = f2b(acc0[j][0] + acc1[j][0]);
    o0[2*j+1] = f2b(acc0[j][1] + acc1[j][1]);
    o1[2*j]   = f2b(acc0[4+j][0] + acc1[4+j][0]);
    o1[2*j+1] = f2b(acc0[4+j][1] + acc1[4+j][1]);
  }
  u16* op = out + (size_t)bq * 768 + h * 48 + d16 * 16;
  *(u16x8*)op = o0;
  *(u16x8*)(op + 8) = o1;
}

// ---------------- launch ----------------
extern "C" void kernel_launch(void* const* d_in, const int* in_sizes, int n_in,
                              void* d_out, int out_size, void* d_ws, size_t ws_size,
                              hipStream_t stream) {
  (void)in_sizes; (void)n_in; (void)out_size; (void)ws_size;
  const float* src0 = (const float*)d_in[0];
  const float* src1 = (const float*)d_in[1];
  const float* src2 = (const float*)d_in[2];
  const float* src3 = (const float*)d_in[3];
  const float* qn_g = (const float*)d_in[4];
  const float* qn_b = (const float*)d_in[5];
  const float* fn_g = (const float*)d_in[6];
  const float* fn_b = (const float*)d_in[7];
  const float* n1_g = (const float*)d_in[8];
  const float* n1_b = (const float*)d_in[9];
  const float* gamma1 = (const float*)d_in[10];
  const float* gamma2 = (const float*)d_in[11];
  const float* c_Wv  = (const float*)d_in[12]; const float* c_bv   = (const float*)d_in[13];
  const float* c_Woff= (const float*)d_in[14]; const float* c_boff = (const float*)d_in[15];
  const float* c_Wa  = (const float*)d_in[16]; const float* c_ba   = (const float*)d_in[17];
  const float* c_Wo  = (const float*)d_in[18]; const float* c_bo   = (const float*)d_in[19];
  const float* s_Wv  = (const float*)d_in[20]; const float* s_bv   = (const float*)d_in[21];
  const float* s_Woff= (const float*)d_in[22]; const float* s_boff = (const float*)d_in[23];
  const float* s_Wa  = (const float*)d_in[24]; const float* s_ba   = (const float*)d_in[25];
  const float* s_Wo  = (const float*)d_in[26]; const float* s_bo   = (const float*)d_in[27];

  constexpr int Lq = 9216;
  constexpr int Mq = 2 * Lq;      // 18432
  constexpr int Mf = 2 * 14592;   // 29184

  constexpr size_t O_qln   = 8u << 20;
  constexpr size_t O_fln   = O_qln   + (size_t)Mq * 768 * 2;
  constexpr size_t O_valc  = O_fln   + (size_t)Mf * 768 * 2;   // fp8, head-major
  constexpr size_t O_offac = O_valc  + (size_t)Mf * 768;       // bf16 [Mq][768]
  constexpr size_t O_sampc = O_qln;                            // reuse
  constexpr size_t O_attn  = O_fln;                            // reuse, bf16
  constexpr size_t O_attn1 = O_attn  + (size_t)Mq * 768 * 2;   // bf16
  constexpr size_t O_vals  = O_attn1 + (size_t)Mq * 768 * 2;   // fp8, head-major
  constexpr size_t O_offas = O_vals  + (size_t)Mq * 768;       // bf16 [Mq][256]
  constexpr size_t O_samps = O_offas + (size_t)Mq * 256 * 2;   // bf16

  uint8_t* ws = (uint8_t*)d_ws;
  u16* Wbase = (u16*)ws;
  auto Wrow = [&](int r) { return Wbase + (size_t)r * 768; };
  auto Wp = [&](size_t o) { return (u16*)(ws + o); };

  wconv_kernel<<<3072, 256, 0, stream>>>(c_Wv, c_Woff, c_Wa, c_Wo, s_Wv, s_Woff, s_Wa, s_Wo, Wbase);

  // fused LN: src3 stats once -> qln + fln tail; src0/1/2 separately
  ln_src3_kernel<<<Mq, 192, 0, stream>>>(src3, qn_g, qn_b, fn_g, fn_b,
                                         Wp(O_qln), Wp(O_fln));
  ln_feat012_kernel<<<2 * 5376, 192, 0, stream>>>(src0, src1, src2, fn_g, fn_b, Wp(O_fln));

  // value projection (cross): Mf x 768 -> head-major fp8 [b][16][14592][48]
  gemm_kernel<MODE_FP8T, 6, 14592><<<(Mf / 128) * 6, 256, 0, stream>>>(
      Wp(O_fln), Wrow(0), c_bv, nullptr, 768, 768, ws + O_valc, 768,
      nullptr, nullptr, nullptr, nullptr);
  // offsets + attn logits (cross, merged): Mq x 768 bf16
  gemm_kernel<MODE_BF16, 6><<<(Mq / 128) * 6, 256, 0, stream>>>(
      Wp(O_qln), Wrow(768), c_boff, c_ba, 512, 768, Wp(O_offac), 768,
      nullptr, nullptr, nullptr, nullptr);

  samp_c_kernel<<<Mq / 4, 384, 0, stream>>>(ws + O_valc, Wp(O_offac), Wp(O_sampc));

  // output proj (cross) -> attn (bf16)
  gemm_kernel<MODE_BF16, 6><<<(Mq / 128) * 6, 256, 0, stream>>>(
      Wp(O_sampc), Wrow(1536), c_bo, nullptr, 768, 768, Wp(O_attn), 768,
      nullptr, nullptr, nullptr, nullptr);

  ln_rows_b16_kernel<<<Mq, 192, 0, stream>>>(Wp(O_attn), n1_g, n1_b, Wp(O_attn1));

  // value projection (self) -> head-major fp8 [b][16][9216][48]
  gemm_kernel<MODE_FP8T, 6, 9216><<<(Mq / 128) * 6, 256, 0, stream>>>(
      Wp(O_attn1), Wrow(2304), s_bv, nullptr, 768, 768, ws + O_vals, 768,
      nullptr, nullptr, nullptr, nullptr);
  // offsets + attn logits (self, merged): Mq x 256 bf16
  gemm_kernel<MODE_BF16, 2><<<(Mq / 128) * 2, 256, 0, stream>>>(
      Wp(O_attn1), Wrow(3072), s_boff, s_ba, 128, 192, Wp(O_offas), 256,
      nullptr, nullptr, nullptr, nullptr);

  samp_s_kernel<<<Mq / 4, 256, 0, stream>>>(ws + O_vals, Wp(O_offas), Wp(O_samps));

  // final: out = src3 + g1*(attn + g2*(samp_s @ s_Wo + s_bo))
  gemm_kernel<MODE_FINAL, 6><<<(Mq / 128) * 6, 256, 0, stream>>>(
      Wp(O_samps), Wrow(3328), s_bo, nullptr, 768, 768, (float*)d_out, 768,
      Wp(O_attn), src3, gamma1, gamma2);
}

// Round 16
// 329.312 us; speedup vs baseline: 1.0502x; 1.0502x over previous
//
#include <hip/hip_runtime.h>
#include <stdint.h>

typedef unsigned short u16;
typedef __attribute__((ext_vector_type(8))) __bf16 bf16x8;
typedef __attribute__((ext_vector_type(4))) float f32x4;
typedef __attribute__((ext_vector_type(2))) float f32x2;
typedef __attribute__((ext_vector_type(8))) u16 u16x8;
typedef __attribute__((ext_vector_type(4))) u16 u16x4;

#define DEV __device__ __forceinline__

DEV u16 f2b(float f) {
  union { float f; uint32_t u; } v; v.f = f;
  uint32_t u = v.u;
  return (u16)((u + 0x7fffu + ((u >> 16) & 1u)) >> 16);
}
DEV float b2f(u16 h) {
  union { uint32_t u; float f; } v; v.u = ((uint32_t)h) << 16;
  return v.f;
}
DEV float u2f(uint32_t u) {
  union { uint32_t u; float f; } v; v.u = u;
  return v.f;
}
// f32 -> fp8 e4m3 (OCP)
DEV uint8_t f2fp8(float f) {
  return (uint8_t)(__builtin_amdgcn_cvt_pk_fp8_f32(f, f, 0, false) & 0xff);
}
// fused fp8x16 gather-convert-FMA (8 cvt + 8 packed fma)
DEV void fma16f8(f32x2* acc, uint4 v, float w) {
  f32x2 wv = {w, w};
  const uint32_t* pv = (const uint32_t*)&v;
  #pragma unroll
  for (int j = 0; j < 4; ++j) {
    f32x2 lo = __builtin_amdgcn_cvt_pk_f32_fp8(pv[j], false);
    f32x2 hi = __builtin_amdgcn_cvt_pk_f32_fp8(pv[j], true);
    acc[2 * j]     += wv * lo;
    acc[2 * j + 1] += wv * hi;
  }
}

// ---------------- fused weight transpose: 8 regions, tiled 32x32 via LDS ----
__global__ __launch_bounds__(256) void wconv_kernel(
    const float* __restrict__ W0, const float* __restrict__ W1,
    const float* __restrict__ W2, const float* __restrict__ W3,
    const float* __restrict__ W4, const float* __restrict__ W5,
    const float* __restrict__ W6, const float* __restrict__ W7,
    u16* __restrict__ dst) {
  __shared__ float s[32][33];
  int bx = blockIdx.x;            // 0..3071
  int ct = bx / 24;               // column-tile 0..127
  int kt = bx - ct * 24;          // k-tile 0..23
  const float* Wsrc; int N; int rowbase; int c0;
  if (ct < 24)       { Wsrc = W0; N = 768; rowbase = 0;    c0 = ct; }
  else if (ct < 40)  { Wsrc = W1; N = 512; rowbase = 768;  c0 = ct - 24; }
  else if (ct < 48)  { Wsrc = W2; N = 256; rowbase = 1280; c0 = ct - 40; }
  else if (ct < 72)  { Wsrc = W3; N = 768; rowbase = 1536; c0 = ct - 48; }
  else if (ct < 96)  { Wsrc = W4; N = 768; rowbase = 2304; c0 = ct - 72; }
  else if (ct < 100) { Wsrc = W5; N = 128; rowbase = 3072; c0 = ct - 96; }
  else if (ct < 104) { Wsrc = W6; N = 64;  rowbase = 3200; c0 = ct - 100; }
  else               { Wsrc = W7; N = 768; rowbase = 3328; c0 = ct - 104; }
  const int tx = threadIdx.x & 31, ty = threadIdx.x >> 5;
  const int n = c0 * 32 + tx;
  const int k0 = kt * 32;
  #pragma unroll
  for (int j = 0; j < 4; ++j) {
    int k = k0 + ty + j * 8;
    s[ty + j * 8][tx] = (n < N) ? Wsrc[(size_t)k * N + n] : 0.0f;
  }
  __syncthreads();
  #pragma unroll
  for (int j = 0; j < 4; ++j) {
    int nr = c0 * 32 + ty + j * 8;
    dst[(size_t)(rowbase + nr) * 768 + k0 + tx] = f2b(s[tx][ty + j * 8]);
  }
}

// ---------------- layernorm (row of 768), 192 threads, float4 ----------------
DEV void ln_stats(float4 v, int t, float* red, float& mean, float& rstd) {
  float s = v.x + v.y + v.z + v.w;
  float s2 = v.x * v.x + v.y * v.y + v.z * v.z + v.w * v.w;
  #pragma unroll
  for (int m = 1; m < 64; m <<= 1) { s += __shfl_xor(s, m); s2 += __shfl_xor(s2, m); }
  if ((t & 63) == 0) { red[t >> 6] = s; red[3 + (t >> 6)] = s2; }
  __syncthreads();
  float S = red[0] + red[1] + red[2];
  float S2 = red[3] + red[4] + red[5];
  mean = S * (1.0f / 768.0f);
  float var = S2 * (1.0f / 768.0f) - mean * mean;
  rstd = rsqrtf(var + 1e-6f);
}
DEV void ln_emit(float4 v, float mean, float rstd, const float* __restrict__ g,
                 const float* __restrict__ b, u16* __restrict__ o, int t) {
  float4 gv = ((const float4*)g)[t], bv = ((const float4*)b)[t];
  u16x4 ov;
  ov[0] = f2b((v.x - mean) * rstd * gv.x + bv.x);
  ov[1] = f2b((v.y - mean) * rstd * gv.y + bv.y);
  ov[2] = f2b((v.z - mean) * rstd * gv.z + bv.z);
  ov[3] = f2b((v.w - mean) * rstd * gv.w + bv.w);
  *(u16x4*)(o + t * 4) = ov;
}

// fused: src3 rows -> qln (qn gains) AND fln tail (fn gains); stats computed once
__global__ __launch_bounds__(192) void ln_src3_kernel(const float* __restrict__ src3,
    const float* __restrict__ qg, const float* __restrict__ qb,
    const float* __restrict__ fg, const float* __restrict__ fb,
    u16* __restrict__ qln, u16* __restrict__ fln) {
  __shared__ float red[6];
  int row = blockIdx.x;                      // 0..Mq-1
  int bb = row / 9216, pos = row - bb * 9216;
  int t = threadIdx.x;
  float4 v = ((const float4*)(src3 + (size_t)row * 768))[t];
  float mean, rstd;
  ln_stats(v, t, red, mean, rstd);
  ln_emit(v, mean, rstd, qg, qb, qln + (size_t)row * 768, t);
  ln_emit(v, mean, rstd, fg, fb, fln + ((size_t)bb * 14592 + 5376 + pos) * 768, t);
}

// feat LN for src0/1/2 rows only (src3 tail handled by ln_src3_kernel)
__global__ __launch_bounds__(192) void ln_feat012_kernel(const float* __restrict__ s0,
    const float* __restrict__ s1, const float* __restrict__ s2,
    const float* __restrict__ g, const float* __restrict__ b, u16* __restrict__ out) {
  __shared__ float red[6];
  int row = blockIdx.x;                      // 0..2*5376-1
  int bb = row / 5376, pos = row - bb * 5376;
  const float* x;
  if (pos < 256)       x = s0 + ((size_t)bb * 256  + pos) * 768;
  else if (pos < 1280) x = s1 + ((size_t)bb * 1024 + (pos - 256)) * 768;
  else                 x = s2 + ((size_t)bb * 4096 + (pos - 1280)) * 768;
  int t = threadIdx.x;
  float4 v = ((const float4*)x)[t];
  float mean, rstd;
  ln_stats(v, t, red, mean, rstd);
  ln_emit(v, mean, rstd, g, b, out + ((size_t)bb * 14592 + pos) * 768, t);
}

__global__ __launch_bounds__(192) void ln_rows_b16_kernel(const u16* __restrict__ in,
    const float* __restrict__ g, const float* __restrict__ b, u16* __restrict__ out) {
  __shared__ float red[6];
  size_t row = blockIdx.x;
  int t = threadIdx.x;
  u16x4 r = *(const u16x4*)(in + row * 768 + t * 4);
  float4 v = {b2f(r[0]), b2f(r[1]), b2f(r[2]), b2f(r[3])};
  float mean, rstd;
  ln_stats(v, t, red, mean, rstd);
  ln_emit(v, mean, rstd, g, b, out + row * 768, t);
}

// ---------------- bf16 MFMA GEMM, 2-phase double-buffered prefetch ----------
enum { MODE_F32 = 0, MODE_BF16 = 1, MODE_FINAL = 2, MODE_FP8T = 3 };

template <int MODE, int NT, int LROW = 1>
__global__ __launch_bounds__(256) void gemm_kernel(
    const u16* __restrict__ A, const u16* __restrict__ Wt,
    const float* __restrict__ bias1, const float* __restrict__ bias2,
    int split, int nb, void* __restrict__ Cout, int N,
    const u16* __restrict__ attnb, const float* __restrict__ resid,
    const float* __restrict__ g1, const float* __restrict__ g2) {
  constexpr int K = 768;
  __shared__ u16 smem[4 * 128 * 64];
  const int t = threadIdx.x;
  const int lane = t & 63;
  const int w = t >> 6;
  const int wr = w >> 1, wc = w & 1;
  const int chunk = gridDim.x >> 3;
  const int tile = (blockIdx.x & 7) * chunk + (blockIdx.x >> 3);
  const int tm = tile / NT, tn = tile - tm * NT;
  const size_t m0 = (size_t)tm * 128;
  const int n0 = tn * 128;

  f32x4 acc[4][4] = {};

  auto STAGE = [&](int buf, int kt) {
    u16* sA = smem + buf * 16384;
    u16* sB = sA + 8192;
    #pragma unroll
    for (int i = 0; i < 4; ++i) {
      int ci = i * 256 + t;
      int row = ci >> 3, c8 = ci & 7;
      int kc = c8 ^ (row & 7);
      const u16* ga = A + (m0 + row) * K + kt + kc * 8;
      const u16* gb = Wt + ((size_t)n0 + row) * K + kt + kc * 8;
      __builtin_amdgcn_global_load_lds((const __attribute__((address_space(1))) void*)ga,
          (__attribute__((address_space(3))) void*)(sA + ci * 8), 16, 0, 0);
      __builtin_amdgcn_global_load_lds((const __attribute__((address_space(1))) void*)gb,
          (__attribute__((address_space(3))) void*)(sB + ci * 8), 16, 0, 0);
    }
  };

  STAGE(0, 0);
  __syncthreads();
  int cur = 0;
  for (int kt = 0; kt < K; kt += 64) {
    if (kt + 64 < K) STAGE(cur ^ 1, kt + 64);
    const u16* sA = smem + cur * 16384;
    const u16* sB = sA + 8192;
    #pragma unroll
    for (int ks = 0; ks < 2; ++ks) {
      bf16x8 af[4], bfr[4];
      #pragma unroll
      for (int m = 0; m < 4; ++m) {
        int row = wr * 64 + m * 16 + (lane & 15);
        int pc = (ks * 4 + (lane >> 4)) ^ (row & 7);
        af[m] = *(const bf16x8*)(sA + row * 64 + pc * 8);
      }
      #pragma unroll
      for (int n = 0; n < 4; ++n) {
        int row = wc * 64 + n * 16 + (lane & 15);
        int pc = (ks * 4 + (lane >> 4)) ^ (row & 7);
        bfr[n] = *(const bf16x8*)(sB + row * 64 + pc * 8);
      }
      #pragma unroll
      for (int m = 0; m < 4; ++m)
        #pragma unroll
        for (int n = 0; n < 4; ++n)
          acc[m][n] = __builtin_amdgcn_mfma_f32_16x16x32_bf16(af[m], bfr[n], acc[m][n], 0, 0, 0);
    }
    __syncthreads();
    cur ^= 1;
  }

  if constexpr (MODE == MODE_BF16) {
    #pragma unroll
    for (int m = 0; m < 4; ++m) {
      #pragma unroll
      for (int n = 0; n < 4; ++n) {
        int lcol = wc * 64 + n * 16 + (lane & 15);
        int gcol = n0 + lcol;
        float bv = (gcol < split) ? bias1[gcol] : ((gcol < nb) ? bias2[gcol - split] : 0.0f);
        #pragma unroll
        for (int r = 0; r < 4; ++r) {
          int lrow = wr * 64 + m * 16 + (lane >> 4) * 4 + r;
          smem[lrow * 136 + lcol] = f2b(acc[m][n][r] + bv);
        }
      }
    }
    __syncthreads();
    #pragma unroll
    for (int i = 0; i < 8; ++i) {
      int c = t + 256 * i;                 // 0..2047
      int lrow = c >> 4, col8 = (c & 15) * 8;
      u16x8 vv = *(const u16x8*)(smem + lrow * 136 + col8);
      int gcol = n0 + col8;
      size_t grow = m0 + (size_t)lrow;
      *(u16x8*)((u16*)Cout + grow * (size_t)N + gcol) = vv;
    }
  } else if constexpr (MODE == MODE_FP8T) {
    uint8_t* s8 = (uint8_t*)smem;          // 128 rows x 144B stride
    #pragma unroll
    for (int m = 0; m < 4; ++m) {
      #pragma unroll
      for (int n = 0; n < 4; ++n) {
        int lcol = wc * 64 + n * 16 + (lane & 15);
        int gcol = n0 + lcol;
        float bv = (gcol < split) ? bias1[gcol] : ((gcol < nb) ? bias2[gcol - split] : 0.0f);
        #pragma unroll
        for (int r = 0; r < 4; ++r) {
          int lrow = wr * 64 + m * 16 + (lane >> 4) * 4 + r;
          s8[lrow * 144 + lcol] = f2fp8(acc[m][n][r] + bv);
        }
      }
    }
    __syncthreads();
    #pragma unroll
    for (int i = 0; i < 4; ++i) {
      int c = t + 256 * i;                 // 0..1023
      int lrow = c >> 3, col16 = (c & 7) * 16;
      uint4 vv = *(const uint4*)(s8 + lrow * 144 + col16);
      int gcol = n0 + col16;
      size_t grow = m0 + (size_t)lrow;
      int gi = (int)grow;
      int bb = gi / LROW, pos = gi - bb * LROW;
      int hh = gcol / 48, dd = gcol - hh * 48;   // 16 | 48: never crosses a head
      *(uint4*)((uint8_t*)Cout + (((size_t)bb * 16 + hh) * LROW + pos) * 48 + dd) = vv;
    }
  } else {
    #pragma unroll
    for (int m = 0; m < 4; ++m) {
      #pragma unroll
      for (int n = 0; n < 4; ++n) {
        int col = n0 + wc * 64 + n * 16 + (lane & 15);
        float bv = (col < split) ? bias1[col] : ((col < nb) ? bias2[col - split] : 0.0f);
        #pragma unroll
        for (int r = 0; r < 4; ++r) {
          size_t grow = m0 + (size_t)(wr * 64 + m * 16 + (lane >> 4) * 4 + r);
          float v = acc[m][n][r] + bv;
          size_t idx = grow * (size_t)N + col;
          if constexpr (MODE == MODE_F32) {
            ((float*)Cout)[idx] = v;
          } else {
            ((float*)Cout)[idx] = resid[idx] + g1[col] * (b2f(attnb[idx]) + g2[col] * v);
          }
        }
      }
    }
  }
}

// ---------------- deformable sampling: fp8 values, d16 threads --------------
// value: [b][16 heads][LROW][48] fp8 e4m3 head-major; offa bf16.
// 4 queries/block, 256 threads. Phase 1 (t<256, thread=(q,h,l)): descriptors.
// Phase 2 (t<192, thread=(q,h,d16)): 16 channels/thread -> per corner one
// 16B load + 8 cvt_pk_f32_fp8 + 8 packed FMA; dual accumulator banks.
__global__ __launch_bounds__(256, 4) void samp_c_kernel(const uint8_t* __restrict__ value,
    const u16* __restrict__ offa, u16* __restrict__ out) {
  __shared__ uint8_t sdesc[4 * 16 * 528];   // 33792 B
  const int orig = blockIdx.x;
  const int cpx = gridDim.x >> 3;
  const int bq0 = ((orig & 7) * cpx + (orig >> 3)) * 4;
  const int t = threadIdx.x;

  {
    const int qi = t >> 6, h = (t >> 2) & 15, l = t & 3;
    const int bq = bq0 + qi;
    const int b = bq / 9216, q = bq - b * 9216;
    const u16* rw = offa + (size_t)bq * 768;
    u16x8 A0 = *(const u16x8*)(rw + 512 + h * 16);
    u16x8 A1 = *(const u16x8*)(rw + 512 + h * 16 + 8);
    float lg[16];
    #pragma unroll
    for (int i = 0; i < 8; ++i) { lg[i] = b2f(A0[i]); lg[8 + i] = b2f(A1[i]); }
    float mx = lg[0];
    #pragma unroll
    for (int i = 1; i < 16; ++i) mx = fmaxf(mx, lg[i]);
    float sum = 0.0f;
    #pragma unroll
    for (int i = 0; i < 16; ++i) sum += __expf(lg[i] - mx);
    const float rs = 1.0f / sum;
    float w0 = (l == 0) ? lg[0] : ((l == 1) ? lg[4] : ((l == 2) ? lg[8]  : lg[12]));
    float w1 = (l == 0) ? lg[1] : ((l == 1) ? lg[5] : ((l == 2) ? lg[9]  : lg[13]));
    float w2 = (l == 0) ? lg[2] : ((l == 1) ? lg[6] : ((l == 2) ? lg[10] : lg[14]));
    float w3 = (l == 0) ? lg[3] : ((l == 1) ? lg[7] : ((l == 2) ? lg[11] : lg[15]));

    const int Wd = (l == 3) ? 96 : (16 << l);
    const int STl = (l == 0) ? 0 : ((l == 1) ? 256 : ((l == 2) ? 1280 : 5376));
    const float fW = (float)Wd;
    const float rx = ((q % 96) + 0.5f) * (1.0f / 96.0f);
    const float ry = ((q / 96) + 0.5f) * (1.0f / 96.0f);
    const int headbase = (b * 16 + h) * 14592 + STl;

    u16x8 O = *(const u16x8*)(rw + h * 32 + l * 8);
    float oxs[4] = {b2f(O[0]), b2f(O[2]), b2f(O[4]), b2f(O[6])};
    float oys[4] = {b2f(O[1]), b2f(O[3]), b2f(O[5]), b2f(O[7])};
    float wgs[4] = {w0, w1, w2, w3};
    uint8_t* dpb = sdesc + (qi * 16 + h) * 528 + l * 32;   // slot = pt*4 + l
    #pragma unroll
    for (int pt = 0; pt < 4; ++pt) {
      float px = rx * fW + oxs[pt] - 0.5f;
      float py = ry * fW + oys[pt] - 0.5f;
      float wgt = __expf(wgs[pt] - mx) * rs;
      float x0f = floorf(px), y0f = floorf(py);
      float lx = px - x0f, ly = py - y0f;
      int x0 = (int)x0f, y0 = (int)y0f;
      int xc0 = min(max(x0, 0), Wd - 1), xc1 = min(max(x0 + 1, 0), Wd - 1);
      int yc0 = min(max(y0, 0), Wd - 1), yc1 = min(max(y0 + 1, 0), Wd - 1);
      float wx0 = ((unsigned)x0       < (unsigned)Wd) ? (1.0f - lx) : 0.0f;
      float wx1 = ((unsigned)(x0 + 1) < (unsigned)Wd) ? lx          : 0.0f;
      float wy0 = (((unsigned)y0       < (unsigned)Wd) ? (1.0f - ly) : 0.0f) * wgt;
      float wy1 = (((unsigned)(y0 + 1) < (unsigned)Wd) ? ly          : 0.0f) * wgt;
      int4 ii;
      ii.x = (headbase + yc0 * Wd + xc0) * 48;
      ii.y = (headbase + yc0 * Wd + xc1) * 48;
      ii.z = (headbase + yc1 * Wd + xc0) * 48;
      ii.w = (headbase + yc1 * Wd + xc1) * 48;
      float4 ww = {wx0 * wy0, wx1 * wy0, wx0 * wy1, wx1 * wy1};
      *(int4*)(dpb + pt * 128) = ii;
      *(float4*)(dpb + pt * 128 + 16) = ww;
    }
  }
  __syncthreads();
  if (t >= 192) return;

  const int qi = t / 48, r = t - qi * 48;
  const int h = r / 3, d16 = r - h * 3;
  const int bq = bq0 + qi;
  const int hd = d16 * 16;
  const uint8_t* vB = value;
  const uint8_t* dp = sdesc + (qi * 16 + h) * 528;

  f32x2 acc0[8] = {}, acc1[8] = {};
  #pragma unroll
  for (int p = 0; p < 16; ++p) {
    const uint8_t* dpp = dp + p * 32;
    int4   ii = *(const int4*)(dpp);
    float4 ww = *(const float4*)(dpp + 16);
    uint4 g0 = *(const uint4*)(vB + (ii.x + hd));
    uint4 g1 = *(const uint4*)(vB + (ii.y + hd));
    uint4 g2 = *(const uint4*)(vB + (ii.z + hd));
    uint4 g3 = *(const uint4*)(vB + (ii.w + hd));
    fma16f8(acc0, g0, ww.x);
    fma16f8(acc1, g1, ww.y);
    fma16f8(acc0, g2, ww.z);
    fma16f8(acc1, g3, ww.w);
  }
  u16x8 o0, o1;
  #pragma unroll
  for (int j = 0; j < 4; ++j) {
    o0[2*j]   = f2b(acc0[j][0] + acc1[j][0]);
    o0[2*j+1] = f2b(acc0[j][1] + acc1[j][1]);
    o1[2*j]   = f2b(acc0[4+j][0] + acc1[4+j][0]);
    o1[2*j+1] = f2b(acc0[4+j][1] + acc1[4+j][1]);
  }
  u16* op = out + (size_t)bq * 768 + h * 48 + d16 * 16;
  *(u16x8*)op = o0;
  *(u16x8*)(op + 8) = o1;
}

// self-attn sampling: offa (bf16) row = [128 off | 64 logits | 64 pad], stride 256.
// value: [b][16][9216][48] fp8. 4 queries/block, 256 threads, d16 phase 2.
__global__ __launch_bounds__(256, 4) void samp_s_kernel(const uint8_t* __restrict__ value,
    const u16* __restrict__ offa, u16* __restrict__ out) {
  __shared__ uint8_t sdesc[4 * 16 * 144];   // 9216 B
  const int orig = blockIdx.x;
  const int cpx = gridDim.x >> 3;
  const int bq0 = ((orig & 7) * cpx + (orig >> 3)) * 4;
  const int t = threadIdx.x;

  if (t < 64) {
    const int qi = t >> 4, h = t & 15;
    const int bq = bq0 + qi;
    const int b = bq / 9216, q = bq - b * 9216;
    const u16* rw = offa + (size_t)bq * 256;
    u16x4 Lv = *(const u16x4*)(rw + 128 + h * 4);
    float lg[4] = {b2f(Lv[0]), b2f(Lv[1]), b2f(Lv[2]), b2f(Lv[3])};
    float mx = fmaxf(fmaxf(lg[0], lg[1]), fmaxf(lg[2], lg[3]));
    float sum = __expf(lg[0] - mx) + __expf(lg[1] - mx) + __expf(lg[2] - mx) + __expf(lg[3] - mx);
    const float rs = 1.0f / sum;
    const float rx = ((q % 96) + 0.5f) * (1.0f / 96.0f);
    const float ry = ((q / 96) + 0.5f) * (1.0f / 96.0f);
    const int headbase = (b * 16 + h) * 9216;
    u16x8 O = *(const u16x8*)(rw + h * 8);
    float oxs[4] = {b2f(O[0]), b2f(O[2]), b2f(O[4]), b2f(O[6])};
    float oys[4] = {b2f(O[1]), b2f(O[3]), b2f(O[5]), b2f(O[7])};
    uint8_t* dpb = sdesc + (qi * 16 + h) * 144;
    #pragma unroll
    for (int pt = 0; pt < 4; ++pt) {
      float px = rx * 96.0f + oxs[pt] - 0.5f;
      float py = ry * 96.0f + oys[pt] - 0.5f;
      float wgt = __expf(lg[pt] - mx) * rs;
      float x0f = floorf(px), y0f = floorf(py);
      float lx = px - x0f, ly = py - y0f;
      int x0 = (int)x0f, y0 = (int)y0f;
      int xc0 = min(max(x0, 0), 95), xc1 = min(max(x0 + 1, 0), 95);
      int yc0 = min(max(y0, 0), 95), yc1 = min(max(y0 + 1, 0), 95);
      float wx0 = ((unsigned)x0       < 96u) ? (1.0f - lx) : 0.0f;
      float wx1 = ((unsigned)(x0 + 1) < 96u) ? lx          : 0.0f;
      float wy0 = (((unsigned)y0       < 96u) ? (1.0f - ly) : 0.0f) * wgt;
      float wy1 = (((unsigned)(y0 + 1) < 96u) ? ly          : 0.0f) * wgt;
      int4 ii;
      ii.x = (headbase + yc0 * 96 + xc0) * 48;
      ii.y = (headbase + yc0 * 96 + xc1) * 48;
      ii.z = (headbase + yc1 * 96 + xc0) * 48;
      ii.w = (headbase + yc1 * 96 + xc1) * 48;
      float4 ww = {wx0 * wy0, wx1 * wy0, wx0 * wy1, wx1 * wy1};
      *(int4*)(dpb + pt * 32) = ii;
      *(float4*)(dpb + pt * 32 + 16) = ww;
    }
  }
  __syncthreads();
  if (t >= 192) return;

  const int qi = t / 48, r = t - qi * 48;
  const int h = r / 3, d16 = r - h * 3;
  const int bq = bq0 + qi;
  const int hd = d16 * 16;
  const uint8_t* vB = value;
  const uint8_t* dp = sdesc + (qi * 16 + h) * 144;

  f32x2 acc0[8] = {}, acc1[8] = {};
  #pragma unroll
  for (int p = 0; p < 4; ++p) {
    const uint8_t* dpp = dp + p * 32;
    int4   ii = *(const int4*)(dpp);
    float4 ww = *(const float4*)(dpp + 16);
    uint4 g0 = *(const uint4*)(vB + (ii.x + hd));
    uint4 g1 = *(const uint4*)(vB + (ii.y + hd));
    uint4 g2 = *(const uint4*)(vB + (ii.z + hd));
    uint4 g3 = *(const uint4*)(vB + (ii.w + hd));
    fma16f8(acc0, g0, ww.x);
    fma16f8(acc1, g1, ww.y);
    fma16f8(acc0, g2, ww.z);
    fma16f8(acc1, g3, ww.w);
  }
  u16x8 o0, o1;
  #pragma unroll
  for (int j = 0; j < 4; ++j) {
    o0[2*j]   = f2b(acc0[j][0] + acc1[j][0]);
    o0[2*j+1] = f2b(acc0[j][1] + acc1[j][1]);
    o1[2*j]   = f2b(acc0[4+j][0] + acc1[4+j][0]);
    o1[2*j+1] = f2b(acc0[4+j][1] + acc1[4+j][1]);
  }
  u16* op = out + (size_t)bq * 768 + h * 48 + d16 * 16;
  *(u16x8*)op = o0;
  *(u16x8*)(op + 8) = o1;
}

// ---------------- launch ----------------
extern "C" void kernel_launch(void* const* d_in, const int* in_sizes, int n_in,
                              void* d_out, int out_size, void* d_ws, size_t ws_size,
                              hipStream_t stream) {
  (void)in_sizes; (void)n_in; (void)out_size; (void)ws_size;
  const float* src0 = (const float*)d_in[0];
  const float* src1 = (const float*)d_in[1];
  const float* src2 = (const float*)d_in[2];
  const float* src3 = (const float*)d_in[3];
  const float* qn_g = (const float*)d_in[4];
  const float* qn_b = (const float*)d_in[5];
  const float* fn_g = (const float*)d_in[6];
  const float* fn_b = (const float*)d_in[7];
  const float* n1_g = (const float*)d_in[8];
  const float* n1_b = (const float*)d_in[9];
  const float* gamma1 = (const float*)d_in[10];
  const float* gamma2 = (const float*)d_in[11];
  const float* c_Wv  = (const float*)d_in[12]; const float* c_bv   = (const float*)d_in[13];
  const float* c_Woff= (const float*)d_in[14]; const float* c_boff = (const float*)d_in[15];
  const float* c_Wa  = (const float*)d_in[16]; const float* c_ba   = (const float*)d_in[17];
  const float* c_Wo  = (const float*)d_in[18]; const float* c_bo   = (const float*)d_in[19];
  const float* s_Wv  = (const float*)d_in[20]; const float* s_bv   = (const float*)d_in[21];
  const float* s_Woff= (const float*)d_in[22]; const float* s_boff = (const float*)d_in[23];
  const float* s_Wa  = (const float*)d_in[24]; const float* s_ba   = (const float*)d_in[25];
  const float* s_Wo  = (const float*)d_in[26]; const float* s_bo   = (const float*)d_in[27];

  constexpr int Lq = 9216;
  constexpr int Mq = 2 * Lq;      // 18432
  constexpr int Mf = 2 * 14592;   // 29184

  constexpr size_t O_qln   = 8u << 20;
  constexpr size_t O_fln   = O_qln   + (size_t)Mq * 768 * 2;
  constexpr size_t O_valc  = O_fln   + (size_t)Mf * 768 * 2;   // fp8, head-major
  constexpr size_t O_offac = O_valc  + (size_t)Mf * 768;       // bf16 [Mq][768]
  constexpr size_t O_sampc = O_qln;                            // reuse
  constexpr size_t O_attn  = O_fln;                            // reuse, bf16
  constexpr size_t O_attn1 = O_attn  + (size_t)Mq * 768 * 2;   // bf16
  constexpr size_t O_vals  = O_attn1 + (size_t)Mq * 768 * 2;   // fp8, head-major
  constexpr size_t O_offas = O_vals  + (size_t)Mq * 768;       // bf16 [Mq][256]
  constexpr size_t O_samps = O_offas + (size_t)Mq * 256 * 2;   // bf16

  uint8_t* ws = (uint8_t*)d_ws;
  u16* Wbase = (u16*)ws;
  auto Wrow = [&](int r) { return Wbase + (size_t)r * 768; };
  auto Wp = [&](size_t o) { return (u16*)(ws + o); };

  wconv_kernel<<<3072, 256, 0, stream>>>(c_Wv, c_Woff, c_Wa, c_Wo, s_Wv, s_Woff, s_Wa, s_Wo, Wbase);

  // fused LN: src3 stats once -> qln + fln tail; src0/1/2 separately
  ln_src3_kernel<<<Mq, 192, 0, stream>>>(src3, qn_g, qn_b, fn_g, fn_b,
                                         Wp(O_qln), Wp(O_fln));
  ln_feat012_kernel<<<2 * 5376, 192, 0, stream>>>(src0, src1, src2, fn_g, fn_b, Wp(O_fln));

  // value projection (cross): Mf x 768 -> head-major fp8 [b][16][14592][48]
  gemm_kernel<MODE_FP8T, 6, 14592><<<(Mf / 128) * 6, 256, 0, stream>>>(
      Wp(O_fln), Wrow(0), c_bv, nullptr, 768, 768, ws + O_valc, 768,
      nullptr, nullptr, nullptr, nullptr);
  // offsets + attn logits (cross, merged): Mq x 768 bf16
  gemm_kernel<MODE_BF16, 6><<<(Mq / 128) * 6, 256, 0, stream>>>(
      Wp(O_qln), Wrow(768), c_boff, c_ba, 512, 768, Wp(O_offac), 768,
      nullptr, nullptr, nullptr, nullptr);

  samp_c_kernel<<<Mq / 4, 256, 0, stream>>>(ws + O_valc, Wp(O_offac), Wp(O_sampc));

  // output proj (cross) -> attn (bf16)
  gemm_kernel<MODE_BF16, 6><<<(Mq / 128) * 6, 256, 0, stream>>>(
      Wp(O_sampc), Wrow(1536), c_bo, nullptr, 768, 768, Wp(O_attn), 768,
      nullptr, nullptr, nullptr, nullptr);

  ln_rows_b16_kernel<<<Mq, 192, 0, stream>>>(Wp(O_attn), n1_g, n1_b, Wp(O_attn1));

  // value projection (self) -> head-major fp8 [b][16][9216][48]
  gemm_kernel<MODE_FP8T, 6, 9216><<<(Mq / 128) * 6, 256, 0, stream>>>(
      Wp(O_attn1), Wrow(2304), s_bv, nullptr, 768, 768, ws + O_vals, 768,
      nullptr, nullptr, nullptr, nullptr);
  // offsets + attn logits (self, merged): Mq x 256 bf16
  gemm_kernel<MODE_BF16, 2><<<(Mq / 128) * 2, 256, 0, stream>>>(
      Wp(O_attn1), Wrow(3072), s_boff, s_ba, 128, 192, Wp(O_offas), 256,
      nullptr, nullptr, nullptr, nullptr);

  samp_s_kernel<<<Mq / 4, 256, 0, stream>>>(ws + O_vals, Wp(O_offas), Wp(O_samps));

  // final: out = src3 + g1*(attn + g2*(samp_s @ s_Wo + s_bo))
  gemm_kernel<MODE_FINAL, 6><<<(Mq / 128) * 6, 256, 0, stream>>>(
      Wp(O_samps), Wrow(3328), s_bo, nullptr, 768, 768, (float*)d_out, 768,
      Wp(O_attn), src3, gamma1, gamma2);
}